// Round 17
// baseline (1429.039 us; speedup 1.0000x reference)
//
#include <hip/hip_runtime.h>
#include <hip/hip_bf16.h>
#include <stdint.h>

// ---------------------------------------------------------------------------
// Transformer: 6 layers. R16 (= R15 with call-site fix): qk and v GEMMs
// MERGED into one dispatch: wqkv2[1920][768] = [Wqk zero-padded to K=768
// (scale=sc[k] both halves); Wv], C = xb16 @ wqkv2^T, epilogue branches per
// N-tile (0-7 -> qkb, 8-14 -> blocked V^T). Grid 1560 blocks = 5.7 blocks/CU
// at unchanged per-block economics. Residual bf16-only; BN folds; fused
// stats; GEMM core R8 (4-wave 128x128 / 32KB / XCD panel grouping);
// attn = R14 (2 blocks per (b,h), blocked V^T staging).
// ---------------------------------------------------------------------------

typedef __bf16 bf16x8 __attribute__((ext_vector_type(8)));
typedef __bf16 bf16x4 __attribute__((ext_vector_type(4)));
typedef float  f32x4  __attribute__((ext_vector_type(4)));

#define DIM_  768
#define SCALE_ 0.125f

__device__ __forceinline__ void gload16(const void* g, void* l) {
  __builtin_amdgcn_global_load_lds(
      (__attribute__((address_space(1))) void*)(g),
      (__attribute__((address_space(3))) void*)(l), 16, 0, 0);
}

__device__ __forceinline__ uint32_t cvt_pk_bf16(float lo, float hi) {
  uint32_t r;
  asm("v_cvt_pk_bf16_f32 %0, %1, %2" : "=v"(r) : "v"(lo), "v"(hi));
  return r;
}

// ------------------------- weight transpose + cvt --------------------------
__global__ void transpose_cvt(const float* __restrict__ W, __bf16* __restrict__ WT,
                              int K, int N) {
  __shared__ float t[32][33];
  const size_t zoff = (size_t)blockIdx.z * K * N;
  W  += zoff; WT += zoff;
  const int bx = blockIdx.x * 32;
  const int by = blockIdx.y * 32;
  for (int j = threadIdx.y; j < 32; j += 8)
    t[j][threadIdx.x] = W[(size_t)(by + j) * N + bx + threadIdx.x];
  __syncthreads();
  for (int j = threadIdx.y; j < 32; j += 8)
    WT[(size_t)(bx + j) * K + by + threadIdx.x] = (__bf16)t[threadIdx.x][j];
}

// ------------------------------- cast -------------------------------------
__global__ void cvt_bf16(const float* __restrict__ src, __bf16* __restrict__ dst) {
  const int i = blockIdx.x * 256 + threadIdx.x;
  f32x4 v = *(const f32x4*)(src + (size_t)i * 4);
  bf16x4 o;
  o[0] = (__bf16)v[0]; o[1] = (__bf16)v[1]; o[2] = (__bf16)v[2]; o[3] = (__bf16)v[3];
  *(bf16x4*)(dst + (size_t)i * 4) = o;
}

// ------------------------------ BN stats (layer-0 bn1 only) ----------------
__global__ void bn_stats_part(const float* __restrict__ x, float* __restrict__ part) {
  const int col = blockIdx.x * 256 + threadIdx.x;
  const int r0  = blockIdx.y * 64;
  const float* p = x + (size_t)r0 * DIM_ + col;
  float s = 0.f, s2 = 0.f;
  for (int r = 0; r < 64; ++r) {
    float v = p[(size_t)r * DIM_];
    s += v; s2 += v * v;
  }
  float* q = part + ((size_t)blockIdx.y * DIM_ + col) * 2;
  q[0] = s; q[1] = s2;
}

__global__ void bn_stats_fin(const float* __restrict__ part, const float* __restrict__ g,
                             const float* __restrict__ b, float* __restrict__ sc) {
  const int col = blockIdx.x * 256 + threadIdx.x;
  float s = 0.f, s2 = 0.f;
  for (int p = 0; p < 196; ++p) {
    s  += part[((size_t)p * DIM_ + col) * 2];
    s2 += part[((size_t)p * DIM_ + col) * 2 + 1];
  }
  const float mean = s * (1.f / 12544.f);
  const float var  = s2 * (1.f / 12544.f) - mean * mean;
  const float rstd = rsqrtf(var + 1e-5f);
  const float scale = rstd * g[col];
  sc[col]        = scale;
  sc[DIM_ + col] = b[col] - mean * scale;
}

// finalize from atomically-accumulated [col][2] sums; self-zero for next use
__global__ void bn_fin2(float* __restrict__ acc, const float* __restrict__ g,
                        const float* __restrict__ b, float* __restrict__ sc) {
  const int col = blockIdx.x * 256 + threadIdx.x;
  const float s  = acc[col * 2];
  const float s2 = acc[col * 2 + 1];
  acc[col * 2] = 0.f; acc[col * 2 + 1] = 0.f;
  const float mean = s * (1.f / 12544.f);
  const float var  = s2 * (1.f / 12544.f) - mean * mean;
  const float rstd = rsqrtf(var + 1e-5f);
  const float scale = rstd * g[col];
  sc[col]        = scale;
  sc[DIM_ + col] = b[col] - mean * scale;
}

// --------------------------- BN fold kernels -------------------------------
// fold_qkv: wqkv2[1920][768]: rows 0-1023 = [0(384) | wqkT*sc[384..]],
// rows 1024-1919 = wvT*sc[k].  bqkv2[n] = bias + dot(weights, shift).
__global__ void fold_qkv(const __bf16* __restrict__ wqkT, const __bf16* __restrict__ wvT,
                         const float* __restrict__ bqk, const float* __restrict__ bv,
                         const float* __restrict__ sc,
                         __bf16* __restrict__ wqkv2, float* __restrict__ bqkv2) {
  const int b = blockIdx.x, tid = threadIdx.x;
  if (b < 720) {                         // scale/zero 1920x768
    const int e = b * 2048 + tid * 8;
    const int n = e / 768, k0 = e - (e / 768) * 768;
    bf16x8 o = {};
    if (n < 1024) {
      if (k0 >= 384) {
        bf16x8 w = *(const bf16x8*)(wqkT + (size_t)n * 384 + (k0 - 384));
#pragma unroll
        for (int j = 0; j < 8; ++j) o[j] = (__bf16)((float)w[j] * sc[k0 + j]);
      }
    } else {
      bf16x8 w = *(const bf16x8*)(wvT + (size_t)(n - 1024) * 768 + k0);
#pragma unroll
      for (int j = 0; j < 8; ++j) o[j] = (__bf16)((float)w[j] * sc[k0 + j]);
    }
    *(bf16x8*)(wqkv2 + e) = o;
  } else {                               // bias GEMVs (1920 rows, 4/block)
    const int lane = tid & 63, wv_ = tid >> 6;
    const int idx = (b - 720) * 4 + wv_;
    float acc = 0.f;
    if (idx < 1024) {
      for (int k = lane; k < 384; k += 64)
        acc += (float)wqkT[(size_t)idx * 384 + k] * sc[1152 + k];
#pragma unroll
      for (int off = 32; off; off >>= 1) acc += __shfl_xor(acc, off);
      if (lane == 0) bqkv2[idx] = bqk[idx] + acc;
    } else {
      const int n2 = idx - 1024;
      for (int k = lane; k < 768; k += 64)
        acc += (float)wvT[(size_t)n2 * 768 + k] * sc[768 + k];
#pragma unroll
      for (int off = 32; off; off >>= 1) acc += __shfl_xor(acc, off);
      if (lane == 0) bqkv2[idx] = bv[n2] + acc;
    }
  }
}

__global__ void fold_ffn(const __bf16* __restrict__ w1T, const float* __restrict__ b1,
                         const float* __restrict__ sc,
                         __bf16* __restrict__ w1T2, float* __restrict__ b12) {
  const int b = blockIdx.x, tid = threadIdx.x;
  if (b < 288) {                         // scale w1T (768x768)
    const int e = b * 2048 + tid * 8;
    const int k0 = e % 768;
    bf16x8 w = *(const bf16x8*)(w1T + e);
    bf16x8 o;
#pragma unroll
    for (int j = 0; j < 8; ++j) o[j] = (__bf16)((float)w[j] * sc[k0 + j]);
    *(bf16x8*)(w1T2 + e) = o;
  } else {
    const int lane = tid & 63, wv_ = tid >> 6;
    const int idx = (b - 288) * 4 + wv_;   // < 768
    float acc = 0.f;
    for (int k = lane; k < 768; k += 64)
      acc += (float)w1T[(size_t)idx * 768 + k] * sc[768 + k];
#pragma unroll
    for (int off = 32; off; off >>= 1) acc += __shfl_xor(acc, off);
    if (lane == 0) b12[idx] = b1[idx] + acc;
  }
}

// ------------------------------ GELU apply ---------------------------------
__global__ void bn_gelu_apply(const __bf16* __restrict__ f1, const float* __restrict__ sc,
                              __bf16* __restrict__ h) {
  const int i = blockIdx.x * 256 + threadIdx.x;
  const int c4 = i % 192;
  bf16x4 v4 = *(const bf16x4*)(f1 + (size_t)i * 4);
  f32x4 scl = *(const f32x4*)(sc + c4 * 4);
  f32x4 sh  = *(const f32x4*)(sc + DIM_ + c4 * 4);
  bf16x4 o;
#pragma unroll
  for (int j = 0; j < 4; ++j) {
    float y = (float)v4[j] * scl[j] + sh[j];
    float gl = 0.5f * y * (1.f + erff(y * 0.70710678118654752f));
    o[j] = (__bf16)gl;
  }
  *(bf16x4*)(h + (size_t)i * 4) = o;
}

// -------------------------------- GEMM -------------------------------------
// C[M x N] = A[M x K] @ BT[N x K]^T ; 128x128 tile, BK=64, 256 thr (4 waves).
// Single-buffer 2-phase, 32KB LDS; XCD panel grouping (bid&7 = XCD class).
// EPI 0: outB=bf16(acc+bias[col]).
// EPI 1: fv=(float)res16[idx]+acc+bias[col]; FINAL? outF[idx]=fv : outB[idx]=bf16(fv).
// EPI 3: merged qkv: N-tile<8 -> outB[rr*1024+cc]=bf16; tile>=8 -> blocked
//        V^T via (bf16*)outF: [((bb*8+hq)*112+dd)*224+nn].
// STATS: per-column sum/sumsq of fp32 fv -> statsAcc.
template <int EPI, int STATS, int PANEL_X, int FINAL>
__global__ __launch_bounds__(256, 2) void gemm128(
    const __bf16* __restrict__ A, int lda,
    const __bf16* __restrict__ BT, int K,
    const float* __restrict__ bias,
    __bf16* outB, const __bf16* res16, float* __restrict__ outF, int ldc,
    float* __restrict__ statsAcc, int P, int S) {
  __shared__ __bf16 sA[128 * 64];
  __shared__ __bf16 sB[128 * 64];
  const int bid = blockIdx.x;
  const int xcd = bid & 7, r0b = bid >> 3;
  const int pl = r0b / S, sh = r0b - pl * S;
  const int p = pl * 8 + xcd;
  if (p >= P) return;
  const int mx = PANEL_X ? p : sh;
  const int ny = PANEL_X ? sh : p;

  const int tid = threadIdx.x;
  const int lane = tid & 63, wv = tid >> 6;
  const int l15 = lane & 15, hi = lane >> 4;
  const int m0 = mx * 128, n0 = ny * 128;
  const __bf16* Ab = A + (size_t)m0 * lda;
  const __bf16* Bb = BT + (size_t)n0 * K;
  const int wr = (wv >> 1) * 64, wc = (wv & 1) * 64;

  f32x4 acc[4][4] = {};

#define STAGE(kt)                                                             \
  {                                                                           \
    const int k0_ = (kt) << 6;                                                \
    _Pragma("unroll")                                                         \
    for (int i_ = 0; i_ < 4; ++i_) {                                          \
      const int o_ = i_ * 4096 + tid * 16;                                    \
      const int row_ = o_ >> 7;                                               \
      const int j_ = (o_ >> 4) & 7;                                           \
      const int src_ = (j_ ^ (row_ & 7)) << 3;                                \
      gload16(Ab + (size_t)row_ * lda + k0_ + src_,                           \
              &sA[i_ * 2048 + wv * 512]);                                     \
      gload16(Bb + (size_t)row_ * K + k0_ + src_,                             \
              &sB[i_ * 2048 + wv * 512]);                                     \
    }                                                                         \
  }

  const int nkt = K >> 6;
  for (int kt = 0; kt < nkt; ++kt) {
    if (kt) __syncthreads();
    STAGE(kt);
    asm volatile("s_waitcnt vmcnt(0)" ::: "memory");
    __syncthreads();
    const char* cA = (const char*)sA;
    const char* cB = (const char*)sB;
#pragma unroll
    for (int ks = 0; ks < 2; ++ks) {
      bf16x8 af[4], bfr[4];
#pragma unroll
      for (int m = 0; m < 4; ++m) {
        const int row = wr + m * 16 + l15;
        af[m] = *(const bf16x8*)(cA + row * 128 +
                                 ((ks * 64 + hi * 16) ^ ((row & 7) << 4)));
      }
#pragma unroll
      for (int n = 0; n < 4; ++n) {
        const int row = wc + n * 16 + l15;
        bfr[n] = *(const bf16x8*)(cB + row * 128 +
                                  ((ks * 64 + hi * 16) ^ ((row & 7) << 4)));
      }
#pragma unroll
      for (int m = 0; m < 4; ++m)
#pragma unroll
        for (int n = 0; n < 4; ++n)
          acc[m][n] = __builtin_amdgcn_mfma_f32_16x16x32_bf16(af[m], bfr[n], acc[m][n], 0, 0, 0);
    }
  }
#undef STAGE

  float* scol = (float*)sA;   // sA dead after K-loop; reuse for stats reduce
  if (STATS) {
    __syncthreads();
    scol[tid] = 0.f;
    __syncthreads();
  }

  float cs[4], cs2[4];
  if (STATS)
#pragma unroll
    for (int n = 0; n < 4; ++n) { cs[n] = 0.f; cs2[n] = 0.f; }

#pragma unroll
  for (int m = 0; m < 4; ++m)
#pragma unroll
    for (int n = 0; n < 4; ++n) {
      const int cc = n0 + wc + n * 16 + l15;
      const float bc = bias[cc];
      // EPI==3 v-side: head/dim from cc (uniform over r)
      const int vd = cc - 1024;
      const int hq = vd / 112, dd = vd - hq * 112;
#pragma unroll
      for (int r = 0; r < 4; ++r) {
        const int rr = m0 + wr + m * 16 + hi * 4 + r;
        const float val = acc[m][n][r] + bc;
        float fv;
        if (EPI == 1) {
          const size_t idx = (size_t)rr * ldc + cc;
          fv = (float)res16[idx] + val;
          if (FINAL) outF[idx] = fv;
          else       outB[idx] = (__bf16)fv;
        } else if (EPI == 3) {
          fv = val;
          if (n0 < 1024) {
            outB[(size_t)rr * 1024 + cc] = (__bf16)fv;
          } else {
            const int bbv = rr / 196, nn = rr - bbv * 196;
            ((__bf16*)outF)[((size_t)(bbv * 8 + hq) * 112 + dd) * 224 + nn] = (__bf16)fv;
          }
        } else {
          fv = val;
          outB[(size_t)rr * ldc + cc] = (__bf16)fv;
        }
        if (STATS) { cs[n] += fv; cs2[n] += fv * fv; }
      }
    }

  if (STATS) {
#pragma unroll
    for (int n = 0; n < 4; ++n) {
      float s = cs[n], s2 = cs2[n];
      s += __shfl_xor(s, 16); s2 += __shfl_xor(s2, 16);
      s += __shfl_xor(s, 32); s2 += __shfl_xor(s2, 32);
      if (lane < 16) {
        atomicAdd(&scol[(wc + n * 16 + l15) * 2], s);
        atomicAdd(&scol[(wc + n * 16 + l15) * 2 + 1], s2);
      }
    }
    __syncthreads();
    if (tid < 128) {
      atomicAdd(&statsAcc[(size_t)(n0 + tid) * 2], scol[tid * 2]);
      atomicAdd(&statsAcc[(size_t)(n0 + tid) * 2 + 1], scol[tid * 2 + 1]);
    }
  }
}

// ------------------------------ attention ----------------------------------
// Two blocks per (b,h) (grid 1024): half = bid>>9, pairid = bid & 511.
// V^T blocked [bh][112][224]: staged via contiguous gload16, linear LDS dest
// slot (d,j) <- source chunk j^(d&3); PV reads (c*16)^((d&3)<<4).
#define SVOFF 25088
__global__ __launch_bounds__(512, 1) void attn_kernel(
    const __bf16* __restrict__ qk, const __bf16* __restrict__ vT,
    __bf16* __restrict__ og) {
  __shared__ __align__(16) char smem[75264];
  const int bid = blockIdx.x;
  const int half = bid >> 9, pairid = bid & 511;
  const int bb = pairid >> 3, hh = pairid & 7;
  const int tid = threadIdx.x, lane = tid & 63;
  const int wv = tid >> 6;
  const int l15 = lane & 15, hi = lane >> 4;

  const __bf16* qbase = qk + (size_t)bb * (196 * 1024) + hh * 64;
  const __bf16* kbase = qbase + 512;
  const __bf16* vbase = vT + (size_t)(bb * 8 + hh) * (112 * 224);
  __bf16* obase = og + (size_t)bb * (196 * 896) + hh * 112;

  char* sV = smem + SVOFF;

  for (int s = tid; s < 1568; s += 512) {
    const int n = s >> 3, j = s & 7;
    const int k8 = j ^ (n & 7);
    gload16(kbase + (size_t)n * 1024 + k8 * 8, smem + ((s >> 6) << 10));
  }
  for (int s = tid; s < 112 * 28; s += 512) {
    const int d = s / 28, j = s - d * 28;
    gload16(vbase + d * 224 + ((j ^ (d & 3)) << 3), sV + d * 448 + j * 16);
  }
  asm volatile("s_waitcnt vmcnt(0)" ::: "memory");
  __syncthreads();

  const int qt = half * 7 + wv;
  if (wv < 7 && qt < 13) {
    const int q0 = qt * 16;
    int qn = q0 + l15; if (qn > 195) qn = 195;
    const __bf16* qp = qbase + (size_t)qn * 1024 + hi * 8;
    const bf16x8 qa0 = *(const bf16x8*)(qp);
    const bf16x8 qa1 = *(const bf16x8*)(qp + 32);

    f32x4 s[13] = {};
#pragma unroll
    for (int nf = 0; nf < 13; ++nf) {
      int j = nf * 16 + l15; if (j > 195) j = 195;
      const int sw = (j & 7) << 4;
      const bf16x8 kb0 = *(const bf16x8*)(smem + j * 128 + ((hi * 16) ^ sw));
      const bf16x8 kb1 = *(const bf16x8*)(smem + j * 128 + ((64 + hi * 16) ^ sw));
      s[nf] = __builtin_amdgcn_mfma_f32_16x16x32_bf16(kb0, qa0, s[nf], 0, 0, 0);
      s[nf] = __builtin_amdgcn_mfma_f32_16x16x32_bf16(kb1, qa1, s[nf], 0, 0, 0);
    }

    float mx = -3.0e38f;
#pragma unroll
    for (int nf = 0; nf < 12; ++nf)
#pragma unroll
      for (int r = 0; r < 4; ++r) mx = fmaxf(mx, s[nf][r]);
    if (hi == 0)
#pragma unroll
      for (int r = 0; r < 4; ++r) mx = fmaxf(mx, s[12][r]);
    mx = fmaxf(mx, __shfl_xor(mx, 16));
    mx = fmaxf(mx, __shfl_xor(mx, 32));
    float sum = 0.f;
#pragma unroll
    for (int nf = 0; nf < 12; ++nf)
#pragma unroll
      for (int r = 0; r < 4; ++r) {
        const float pv = __expf((s[nf][r] - mx) * SCALE_);
        s[nf][r] = pv; sum += pv;
      }
#pragma unroll
    for (int r = 0; r < 4; ++r) {
      const float pv = (hi == 0) ? __expf((s[12][r] - mx) * SCALE_) : 0.f;
      s[12][r] = pv; sum += pv;
    }
    sum += __shfl_xor(sum, 16);
    sum += __shfl_xor(sum, 32);
    const float inv = 1.f / sum;
#pragma unroll
    for (int nf = 0; nf < 13; ++nf)
#pragma unroll
      for (int r = 0; r < 4; ++r) s[nf][r] *= inv;

    f32x4 oa[7] = {};
    const int sLo = l15 + ((hi & 1) << 5);
    const int sHi = sLo + 16;
    const bool up = (hi >> 1) != 0;
#pragma unroll
    for (int kk = 0; kk < 7; ++kk) {
      const uint32_t a0 = cvt_pk_bf16(s[2 * kk][0], s[2 * kk][1]);
      const uint32_t a1 = cvt_pk_bf16(s[2 * kk][2], s[2 * kk][3]);
      const uint32_t w0a = (uint32_t)__shfl((int)a0, sLo, 64);
      const uint32_t w1a = (uint32_t)__shfl((int)a1, sLo, 64);
      const uint32_t w2a = (uint32_t)__shfl((int)a0, sHi, 64);
      const uint32_t w3a = (uint32_t)__shfl((int)a1, sHi, 64);
      uint32_t w0, w1, w2, w3;
      if (kk < 6) {
        const uint32_t b0 = cvt_pk_bf16(s[2 * kk + 1][0], s[2 * kk + 1][1]);
        const uint32_t b1 = cvt_pk_bf16(s[2 * kk + 1][2], s[2 * kk + 1][3]);
        const uint32_t w0b = (uint32_t)__shfl((int)b0, sLo, 64);
        const uint32_t w1b = (uint32_t)__shfl((int)b1, sLo, 64);
        const uint32_t w2b = (uint32_t)__shfl((int)b0, sHi, 64);
        const uint32_t w3b = (uint32_t)__shfl((int)b1, sHi, 64);
        w0 = up ? w0b : w0a; w1 = up ? w1b : w1a;
        w2 = up ? w2b : w2a; w3 = up ? w3b : w3a;
      } else {
        w0 = up ? 0u : w0a; w1 = up ? 0u : w1a;
        w2 = up ? 0u : w2a; w3 = up ? 0u : w3a;
      }
      union { uint32_t u[4]; bf16x8 v; } pa;
      pa.u[0] = w0; pa.u[1] = w1; pa.u[2] = w2; pa.u[3] = w3;
#pragma unroll
      for (int nf = 0; nf < 7; ++nf) {
        const int d = nf * 16 + l15;
        const bf16x8 vbf = *(const bf16x8*)(sV + d * 448 +
                              ((kk * 64 + hi * 16) ^ ((d & 3) << 4)));
        oa[nf] = __builtin_amdgcn_mfma_f32_16x16x32_bf16(pa.v, vbf, oa[nf], 0, 0, 0);
      }
    }
#pragma unroll
    for (int nf = 0; nf < 7; ++nf)
#pragma unroll
      for (int r = 0; r < 4; ++r) {
        const int q = q0 + hi * 4 + r;
        if (q < 196) obase[(size_t)q * 896 + nf * 16 + l15] = (__bf16)oa[nf][r];
      }
  }
}

// ------------------------------- launch ------------------------------------
extern "C" void kernel_launch(void* const* d_in, const int* in_sizes, int n_in,
                              void* d_out, int out_size, void* d_ws, size_t ws_size,
                              hipStream_t stream) {
  (void)in_sizes; (void)n_in; (void)out_size; (void)ws_size;
  const float* x_in  = (const float*)d_in[0];
  const float* bn1_g = (const float*)d_in[1];
  const float* bn1_b = (const float*)d_in[2];
  const float* Wqk   = (const float*)d_in[3];
  const float* bqk   = (const float*)d_in[4];
  const float* Wv    = (const float*)d_in[5];
  const float* bv    = (const float*)d_in[6];
  const float* Wo    = (const float*)d_in[7];
  const float* bo    = (const float*)d_in[8];
  const float* bn2_g = (const float*)d_in[9];
  const float* bn2_b = (const float*)d_in[10];
  const float* W1    = (const float*)d_in[11];
  const float* b1    = (const float*)d_in[12];
  const float* bn3_g = (const float*)d_in[13];
  const float* bn3_b = (const float*)d_in[14];
  const float* W2    = (const float*)d_in[15];
  const float* b2    = (const float*)d_in[16];

  char* ws = (char*)d_ws;
  __bf16* vTb  = (__bf16*)(ws + 0);           // 512x112x224 bf16 (blocked V^T)
  __bf16* wqkv2= (__bf16*)(ws + 25690112);    // 1920x768 folded qkv weights
  __bf16* w1T2 = (__bf16*)(ws + 28639232);    // 768x768 folded
  float*  bqkv2= (float*)(ws + 29818880);     // 1920
  float*  b12  = (float*)(ws + 29826560);     // 768
  __bf16* wqkT = (__bf16*)(ws + 38535168);    // 6 x 1024 x 384
  __bf16* wvT  = (__bf16*)(ws + 43253760);    // 6 x 896 x 768
  __bf16* woT  = (__bf16*)(ws + 51511296);    // 6 x 768 x 896
  __bf16* w1T  = (__bf16*)(ws + 59768832);    // 6 x 768 x 768
  __bf16* w2T  = (__bf16*)(ws + 66846720);    // 6 x 768 x 768
  __bf16* xb16 = (__bf16*)(ws + 73924608);    // 12544x768 bf16 (THE residual)
  __bf16* qkb  = (__bf16*)(ws + 93192192);    // 12544x1024 bf16 (also f1 reuse)
  __bf16* obuf = (__bf16*)(ws + 141361152);   // 12544x896 bf16 (attn out; gelu out reuses)
  float*  part = (float*)(ws + 163840000);    // 196x768x2 f32
  float*  sc   = (float*)(ws + 165044224);    // 2x768 f32
  float*  sAcc = (float*)(ws + 165051392);    // 768x2 f32 stats accumulator
  __bf16* f1b  = qkb;
  __bf16* gout = obuf;                        // GELU output reuses obuf region

  const dim3 tb(256);
  const dim3 tb512(512);

  transpose_cvt<<<dim3(32, 12, 6), dim3(32, 8), 0, stream>>>(Wqk, wqkT, 384, 1024);
  transpose_cvt<<<dim3(28, 24, 6), dim3(32, 8), 0, stream>>>(Wv,  wvT,  768, 896);
  transpose_cvt<<<dim3(24, 28, 6), dim3(32, 8), 0, stream>>>(Wo,  woT,  896, 768);
  transpose_cvt<<<dim3(24, 24, 6), dim3(32, 8), 0, stream>>>(W1,  w1T,  768, 768);
  transpose_cvt<<<dim3(24, 24, 6), dim3(32, 8), 0, stream>>>(W2,  w2T,  768, 768);
  cvt_bf16<<<9408, tb, 0, stream>>>(x_in, xb16);
  hipMemsetAsync(sAcc, 0, 768 * 2 * sizeof(float), stream);
  hipMemsetAsync(vTb, 0, (size_t)512 * 112 * 224 * 2, stream);  // zero pad cols

  // layer-0 bn1 stats (standalone, reads x_in fp32 exactly)
  bn_stats_part<<<dim3(3, 196), tb, 0, stream>>>(x_in, part);
  bn_stats_fin<<<3, tb, 0, stream>>>(part, bn1_g, bn1_b, sc);

  // XCD-grouped 1D grids: 8 * ceil(98/8)=13 * S
  const int gQKV = 8 * 13 * 15;   // merged qkv: P=98 M-panels, S=15 N-tiles
  const int gO   = 8 * 13 * 6;

  for (int i = 0; i < 6; ++i) {
    const __bf16* wqkT_i = wqkT + (size_t)i * 1024 * 384;
    const __bf16* wvT_i  = wvT  + (size_t)i * 896 * 768;
    const __bf16* woT_i  = woT  + (size_t)i * 768 * 896;
    const __bf16* w1T_i  = w1T  + (size_t)i * 768 * 768;
    const __bf16* w2T_i  = w2T  + (size_t)i * 768 * 768;

    // --- attention block ---  (sc holds bn1 scale/shift)
    fold_qkv<<<1200, tb, 0, stream>>>(wqkT_i, wvT_i, bqk + i * 1024, bv + i * 896,
                                      sc, wqkv2, bqkv2);
    gemm128<3, 0, 1, 0><<<gQKV, tb, 0, stream>>>(xb16, 768, wqkv2, 768,
                                                 bqkv2, qkb, nullptr, (float*)vTb, 1024,
                                                 nullptr, 98, 15);
    attn_kernel<<<1024, tb512, 0, stream>>>(qkb, vTb, obuf);
    gemm128<1, 1, 1, 0><<<gO, tb, 0, stream>>>(obuf, 896, woT_i, 896,
                                               bo + i * 768, xb16, xb16, nullptr, 768,
                                               sAcc, 98, 6);

    // --- feedforward block ---
    bn_fin2<<<3, tb, 0, stream>>>(sAcc, bn2_g + i * 768, bn2_b + i * 768, sc);
    fold_ffn<<<480, tb, 0, stream>>>(w1T_i, b1 + i * 768, sc, w1T2, b12);
    gemm128<0, 1, 1, 0><<<gO, tb, 0, stream>>>(xb16, 768, w1T2, 768,
                                               b12, f1b, nullptr, nullptr, 768,
                                               sAcc, 98, 6);
    bn_fin2<<<3, tb, 0, stream>>>(sAcc, bn3_g + i * 768, bn3_b + i * 768, sc);
    bn_gelu_apply<<<9408, tb, 0, stream>>>(f1b, sc, gout);
    if (i < 5) {
      gemm128<1, 1, 1, 0><<<gO, tb, 0, stream>>>(gout, 768, w2T_i, 768,
                                                 b2 + i * 768, xb16, xb16, nullptr, 768,
                                                 sAcc, 98, 6);
      bn_fin2<<<3, tb, 0, stream>>>(sAcc, bn1_g + (i + 1) * 768, bn1_b + (i + 1) * 768, sc);
    } else {
      gemm128<1, 0, 1, 1><<<gO, tb, 0, stream>>>(gout, 768, w2T_i, 768,
                                                 b2 + i * 768, xb16, xb16,
                                                 (float*)d_out, 768,
                                                 nullptr, 98, 6);
    }
  }
}

// Round 19
// 1268.716 us; speedup vs baseline: 1.1264x; 1.1264x over previous
//
#include <hip/hip_runtime.h>
#include <hip/hip_bf16.h>
#include <stdint.h>

// ---------------------------------------------------------------------------
// Transformer: 6 layers. R19 = R14 (best measured: 1272 us), call-site fix.
// V^T stored per-(b,h) BLOCKED [512][112][224]; v-GEMM epilogue writes
// blocked offsets (token-contiguous); attn V-staging is contiguous 16B
// gload_lds (linear dest, source chunk ^ (d&3)). Residual bf16-only;
// BN1/BN2 folded into weights; fused BN-stats epilogues; GEMM = R8 4-wave
// 128x128 / 32KB / XCD panel grouping.
// ---------------------------------------------------------------------------

typedef __bf16 bf16x8 __attribute__((ext_vector_type(8)));
typedef __bf16 bf16x4 __attribute__((ext_vector_type(4)));
typedef float  f32x4  __attribute__((ext_vector_type(4)));

#define DIM_  768
#define SCALE_ 0.125f

__device__ __forceinline__ void gload16(const void* g, void* l) {
  __builtin_amdgcn_global_load_lds(
      (__attribute__((address_space(1))) void*)(g),
      (__attribute__((address_space(3))) void*)(l), 16, 0, 0);
}

__device__ __forceinline__ uint32_t cvt_pk_bf16(float lo, float hi) {
  uint32_t r;
  asm("v_cvt_pk_bf16_f32 %0, %1, %2" : "=v"(r) : "v"(lo), "v"(hi));
  return r;
}

// ------------------------- weight transpose + cvt --------------------------
__global__ void transpose_cvt(const float* __restrict__ W, __bf16* __restrict__ WT,
                              int K, int N) {
  __shared__ float t[32][33];
  const size_t zoff = (size_t)blockIdx.z * K * N;
  W  += zoff; WT += zoff;
  const int bx = blockIdx.x * 32;
  const int by = blockIdx.y * 32;
  for (int j = threadIdx.y; j < 32; j += 8)
    t[j][threadIdx.x] = W[(size_t)(by + j) * N + bx + threadIdx.x];
  __syncthreads();
  for (int j = threadIdx.y; j < 32; j += 8)
    WT[(size_t)(bx + j) * K + by + threadIdx.x] = (__bf16)t[threadIdx.x][j];
}

// ------------------------------- cast -------------------------------------
__global__ void cvt_bf16(const float* __restrict__ src, __bf16* __restrict__ dst) {
  const int i = blockIdx.x * 256 + threadIdx.x;
  f32x4 v = *(const f32x4*)(src + (size_t)i * 4);
  bf16x4 o;
  o[0] = (__bf16)v[0]; o[1] = (__bf16)v[1]; o[2] = (__bf16)v[2]; o[3] = (__bf16)v[3];
  *(bf16x4*)(dst + (size_t)i * 4) = o;
}

// ------------------------------ BN stats (layer-0 bn1 only) ----------------
__global__ void bn_stats_part(const float* __restrict__ x, float* __restrict__ part) {
  const int col = blockIdx.x * 256 + threadIdx.x;
  const int r0  = blockIdx.y * 64;
  const float* p = x + (size_t)r0 * DIM_ + col;
  float s = 0.f, s2 = 0.f;
  for (int r = 0; r < 64; ++r) {
    float v = p[(size_t)r * DIM_];
    s += v; s2 += v * v;
  }
  float* q = part + ((size_t)blockIdx.y * DIM_ + col) * 2;
  q[0] = s; q[1] = s2;
}

__global__ void bn_stats_fin(const float* __restrict__ part, const float* __restrict__ g,
                             const float* __restrict__ b, float* __restrict__ sc) {
  const int col = blockIdx.x * 256 + threadIdx.x;
  float s = 0.f, s2 = 0.f;
  for (int p = 0; p < 196; ++p) {
    s  += part[((size_t)p * DIM_ + col) * 2];
    s2 += part[((size_t)p * DIM_ + col) * 2 + 1];
  }
  const float mean = s * (1.f / 12544.f);
  const float var  = s2 * (1.f / 12544.f) - mean * mean;
  const float rstd = rsqrtf(var + 1e-5f);
  const float scale = rstd * g[col];
  sc[col]        = scale;
  sc[DIM_ + col] = b[col] - mean * scale;
}

// finalize from atomically-accumulated [col][2] sums; self-zero for next use
__global__ void bn_fin2(float* __restrict__ acc, const float* __restrict__ g,
                        const float* __restrict__ b, float* __restrict__ sc) {
  const int col = blockIdx.x * 256 + threadIdx.x;
  const float s  = acc[col * 2];
  const float s2 = acc[col * 2 + 1];
  acc[col * 2] = 0.f; acc[col * 2 + 1] = 0.f;
  const float mean = s * (1.f / 12544.f);
  const float var  = s2 * (1.f / 12544.f) - mean * mean;
  const float rstd = rsqrtf(var + 1e-5f);
  const float scale = rstd * g[col];
  sc[col]        = scale;
  sc[DIM_ + col] = b[col] - mean * scale;
}

// --------------------------- BN fold kernels -------------------------------
__global__ void fold_attn(const __bf16* __restrict__ wqkT, const __bf16* __restrict__ wvT,
                          const float* __restrict__ bqk, const float* __restrict__ bv,
                          const float* __restrict__ sc,
                          __bf16* __restrict__ wqkT2, __bf16* __restrict__ wvT2,
                          float* __restrict__ bqk2, float* __restrict__ bv2) {
  const int b = blockIdx.x, tid = threadIdx.x;
  if (b < 192) {                         // scale wqkT (1024x384)
    const int e = b * 2048 + tid * 8;
    const int k0 = e % 384;
    bf16x8 w = *(const bf16x8*)(wqkT + e);
    bf16x8 o;
#pragma unroll
    for (int j = 0; j < 8; ++j) o[j] = (__bf16)((float)w[j] * sc[384 + k0 + j]);
    *(bf16x8*)(wqkT2 + e) = o;
  } else if (b < 528) {                  // scale wvT (896x768)
    const int e = (b - 192) * 2048 + tid * 8;
    const int k0 = e % 768;
    bf16x8 w = *(const bf16x8*)(wvT + e);
    bf16x8 o;
#pragma unroll
    for (int j = 0; j < 8; ++j) o[j] = (__bf16)((float)w[j] * sc[k0 + j]);
    *(bf16x8*)(wvT2 + e) = o;
  } else {                               // bias GEMVs (1024 + 896 rows)
    const int lane = tid & 63, wv_ = tid >> 6;
    const int idx = (b - 528) * 4 + wv_;
    float acc = 0.f;
    if (idx < 1024) {
      for (int k = lane; k < 384; k += 64)
        acc += (float)wqkT[(size_t)idx * 384 + k] * sc[1152 + k];
#pragma unroll
      for (int off = 32; off; off >>= 1) acc += __shfl_xor(acc, off);
      if (lane == 0) bqk2[idx] = bqk[idx] + acc;
    } else {
      const int n2 = idx - 1024;
      for (int k = lane; k < 768; k += 64)
        acc += (float)wvT[(size_t)n2 * 768 + k] * sc[768 + k];
#pragma unroll
      for (int off = 32; off; off >>= 1) acc += __shfl_xor(acc, off);
      if (lane == 0) bv2[n2] = bv[n2] + acc;
    }
  }
}

__global__ void fold_ffn(const __bf16* __restrict__ w1T, const float* __restrict__ b1,
                         const float* __restrict__ sc,
                         __bf16* __restrict__ w1T2, float* __restrict__ b12) {
  const int b = blockIdx.x, tid = threadIdx.x;
  if (b < 288) {                         // scale w1T (768x768)
    const int e = b * 2048 + tid * 8;
    const int k0 = e % 768;
    bf16x8 w = *(const bf16x8*)(w1T + e);
    bf16x8 o;
#pragma unroll
    for (int j = 0; j < 8; ++j) o[j] = (__bf16)((float)w[j] * sc[k0 + j]);
    *(bf16x8*)(w1T2 + e) = o;
  } else {
    const int lane = tid & 63, wv_ = tid >> 6;
    const int idx = (b - 288) * 4 + wv_;   // < 768
    float acc = 0.f;
    for (int k = lane; k < 768; k += 64)
      acc += (float)w1T[(size_t)idx * 768 + k] * sc[768 + k];
#pragma unroll
    for (int off = 32; off; off >>= 1) acc += __shfl_xor(acc, off);
    if (lane == 0) b12[idx] = b1[idx] + acc;
  }
}

// ------------------------------ GELU apply ---------------------------------
__global__ void bn_gelu_apply(const __bf16* __restrict__ f1, const float* __restrict__ sc,
                              __bf16* __restrict__ h) {
  const int i = blockIdx.x * 256 + threadIdx.x;
  const int c4 = i % 192;
  bf16x4 v4 = *(const bf16x4*)(f1 + (size_t)i * 4);
  f32x4 scl = *(const f32x4*)(sc + c4 * 4);
  f32x4 sh  = *(const f32x4*)(sc + DIM_ + c4 * 4);
  bf16x4 o;
#pragma unroll
  for (int j = 0; j < 4; ++j) {
    float y = (float)v4[j] * scl[j] + sh[j];
    float gl = 0.5f * y * (1.f + erff(y * 0.70710678118654752f));
    o[j] = (__bf16)gl;
  }
  *(bf16x4*)(h + (size_t)i * 4) = o;
}

// -------------------------------- GEMM -------------------------------------
// C[M x N] = A[M x K] @ BT[N x K]^T ; 128x128 tile, BK=64, 256 thr (4 waves).
// Single-buffer 2-phase, 32KB LDS; XCD panel grouping (bid&7 = XCD class).
// EPI 0: outB=bf16(acc+bias[col]).
// EPI 1: fv=(float)res16[idx]+acc+bias[col]; FINAL? outF[idx]=fv : outB[idx]=bf16(fv).
// EPI 2: V^T blocked write: row rr=hh*112+d, col cc=bb*196+n ->
//        outB[((bb*8+hq)*112+dd)*224+nn] = bf16(acc+bias[rr]).
// STATS: per-column sum/sumsq of fp32 fv -> statsAcc.
template <int EPI, int STATS, int PANEL_X, int FINAL>
__global__ __launch_bounds__(256, 2) void gemm128(
    const __bf16* __restrict__ A, int lda,
    const __bf16* __restrict__ BT, int K,
    const float* __restrict__ bias,
    __bf16* outB, const __bf16* res16, float* __restrict__ outF, int ldc,
    float* __restrict__ statsAcc, int P, int S) {
  __shared__ __bf16 sA[128 * 64];
  __shared__ __bf16 sB[128 * 64];
  const int bid = blockIdx.x;
  const int xcd = bid & 7, r0b = bid >> 3;
  const int pl = r0b / S, sh = r0b - pl * S;
  const int p = pl * 8 + xcd;
  if (p >= P) return;
  const int mx = PANEL_X ? p : sh;
  const int ny = PANEL_X ? sh : p;

  const int tid = threadIdx.x;
  const int lane = tid & 63, wv = tid >> 6;
  const int l15 = lane & 15, hi = lane >> 4;
  const int m0 = mx * 128, n0 = ny * 128;
  const __bf16* Ab = A + (size_t)m0 * lda;
  const __bf16* Bb = BT + (size_t)n0 * K;
  const int wr = (wv >> 1) * 64, wc = (wv & 1) * 64;

  f32x4 acc[4][4] = {};

#define STAGE(kt)                                                             \
  {                                                                           \
    const int k0_ = (kt) << 6;                                                \
    _Pragma("unroll")                                                         \
    for (int i_ = 0; i_ < 4; ++i_) {                                          \
      const int o_ = i_ * 4096 + tid * 16;                                    \
      const int row_ = o_ >> 7;                                               \
      const int j_ = (o_ >> 4) & 7;                                           \
      const int src_ = (j_ ^ (row_ & 7)) << 3;                                \
      gload16(Ab + (size_t)row_ * lda + k0_ + src_,                           \
              &sA[i_ * 2048 + wv * 512]);                                     \
      gload16(Bb + (size_t)row_ * K + k0_ + src_,                             \
              &sB[i_ * 2048 + wv * 512]);                                     \
    }                                                                         \
  }

  const int nkt = K >> 6;
  for (int kt = 0; kt < nkt; ++kt) {
    if (kt) __syncthreads();
    STAGE(kt);
    asm volatile("s_waitcnt vmcnt(0)" ::: "memory");
    __syncthreads();
    const char* cA = (const char*)sA;
    const char* cB = (const char*)sB;
#pragma unroll
    for (int ks = 0; ks < 2; ++ks) {
      bf16x8 af[4], bfr[4];
#pragma unroll
      for (int m = 0; m < 4; ++m) {
        const int row = wr + m * 16 + l15;
        af[m] = *(const bf16x8*)(cA + row * 128 +
                                 ((ks * 64 + hi * 16) ^ ((row & 7) << 4)));
      }
#pragma unroll
      for (int n = 0; n < 4; ++n) {
        const int row = wc + n * 16 + l15;
        bfr[n] = *(const bf16x8*)(cB + row * 128 +
                                  ((ks * 64 + hi * 16) ^ ((row & 7) << 4)));
      }
#pragma unroll
      for (int m = 0; m < 4; ++m)
#pragma unroll
        for (int n = 0; n < 4; ++n)
          acc[m][n] = __builtin_amdgcn_mfma_f32_16x16x32_bf16(af[m], bfr[n], acc[m][n], 0, 0, 0);
    }
  }
#undef STAGE

  float* scol = (float*)sA;   // sA dead after K-loop; reuse for stats reduce
  if (STATS) {
    __syncthreads();
    scol[tid] = 0.f;
    __syncthreads();
  }

  float cs[4], cs2[4];
  if (STATS)
#pragma unroll
    for (int n = 0; n < 4; ++n) { cs[n] = 0.f; cs2[n] = 0.f; }

#pragma unroll
  for (int m = 0; m < 4; ++m)
#pragma unroll
    for (int n = 0; n < 4; ++n) {
      const int cc = n0 + wc + n * 16 + l15;
      const float bc = (EPI == 2) ? 0.f : bias[cc];
      const int bbq = cc / 196, nn = cc - (cc / 196) * 196;   // EPI==2 only
#pragma unroll
      for (int r = 0; r < 4; ++r) {
        const int rr = m0 + wr + m * 16 + hi * 4 + r;
        const float val = acc[m][n][r] + ((EPI == 2) ? bias[rr] : bc);
        float fv;
        if (EPI == 1) {
          const size_t idx = (size_t)rr * ldc + cc;
          fv = (float)res16[idx] + val;
          if (FINAL) outF[idx] = fv;
          else       outB[idx] = (__bf16)fv;
        } else if (EPI == 2) {
          fv = val;
          const int hq = rr / 112, dd = rr - (rr / 112) * 112;
          outB[((size_t)(bbq * 8 + hq) * 112 + dd) * 224 + nn] = (__bf16)fv;
        } else {
          fv = val;
          outB[(size_t)rr * ldc + cc] = (__bf16)fv;
        }
        if (STATS) { cs[n] += fv; cs2[n] += fv * fv; }
      }
    }

  if (STATS) {
#pragma unroll
    for (int n = 0; n < 4; ++n) {
      float s = cs[n], s2 = cs2[n];
      s += __shfl_xor(s, 16); s2 += __shfl_xor(s2, 16);
      s += __shfl_xor(s, 32); s2 += __shfl_xor(s2, 32);
      if (lane < 16) {
        atomicAdd(&scol[(wc + n * 16 + l15) * 2], s);
        atomicAdd(&scol[(wc + n * 16 + l15) * 2 + 1], s2);
      }
    }
    __syncthreads();
    if (tid < 128) {
      atomicAdd(&statsAcc[(size_t)(n0 + tid) * 2], scol[tid * 2]);
      atomicAdd(&statsAcc[(size_t)(n0 + tid) * 2 + 1], scol[tid * 2 + 1]);
    }
  }
}

// ------------------------------ attention ----------------------------------
// Two blocks per (b,h) (grid 1024): half = bid>>9, pairid = bid & 511.
// V^T blocked [bh][112][224]: staged via contiguous gload16, linear LDS dest
// slot (d,j) <- source chunk j^(d&3); PV reads (c*16)^((d&3)<<4).
#define SVOFF 25088
__global__ __launch_bounds__(512, 1) void attn_kernel(
    const __bf16* __restrict__ qk, const __bf16* __restrict__ vT,
    __bf16* __restrict__ og) {
  __shared__ __align__(16) char smem[75264];
  const int bid = blockIdx.x;
  const int half = bid >> 9, pairid = bid & 511;
  const int bb = pairid >> 3, hh = pairid & 7;
  const int tid = threadIdx.x, lane = tid & 63;
  const int wv = tid >> 6;
  const int l15 = lane & 15, hi = lane >> 4;

  const __bf16* qbase = qk + (size_t)bb * (196 * 1024) + hh * 64;
  const __bf16* kbase = qbase + 512;
  const __bf16* vbase = vT + (size_t)(bb * 8 + hh) * (112 * 224);
  __bf16* obase = og + (size_t)bb * (196 * 896) + hh * 112;

  char* sV = smem + SVOFF;

  for (int s = tid; s < 1568; s += 512) {
    const int n = s >> 3, j = s & 7;
    const int k8 = j ^ (n & 7);
    gload16(kbase + (size_t)n * 1024 + k8 * 8, smem + ((s >> 6) << 10));
  }
  for (int s = tid; s < 112 * 28; s += 512) {
    const int d = s / 28, j = s - d * 28;
    gload16(vbase + d * 224 + ((j ^ (d & 3)) << 3), sV + d * 448 + j * 16);
  }
  asm volatile("s_waitcnt vmcnt(0)" ::: "memory");
  __syncthreads();

  const int qt = half * 7 + wv;
  if (wv < 7 && qt < 13) {
    const int q0 = qt * 16;
    int qn = q0 + l15; if (qn > 195) qn = 195;
    const __bf16* qp = qbase + (size_t)qn * 1024 + hi * 8;
    const bf16x8 qa0 = *(const bf16x8*)(qp);
    const bf16x8 qa1 = *(const bf16x8*)(qp + 32);

    f32x4 s[13] = {};
#pragma unroll
    for (int nf = 0; nf < 13; ++nf) {
      int j = nf * 16 + l15; if (j > 195) j = 195;
      const int sw = (j & 7) << 4;
      const bf16x8 kb0 = *(const bf16x8*)(smem + j * 128 + ((hi * 16) ^ sw));
      const bf16x8 kb1 = *(const bf16x8*)(smem + j * 128 + ((64 + hi * 16) ^ sw));
      s[nf] = __builtin_amdgcn_mfma_f32_16x16x32_bf16(kb0, qa0, s[nf], 0, 0, 0);
      s[nf] = __builtin_amdgcn_mfma_f32_16x16x32_bf16(kb1, qa1, s[nf], 0, 0, 0);
    }

    float mx = -3.0e38f;
#pragma unroll
    for (int nf = 0; nf < 12; ++nf)
#pragma unroll
      for (int r = 0; r < 4; ++r) mx = fmaxf(mx, s[nf][r]);
    if (hi == 0)
#pragma unroll
      for (int r = 0; r < 4; ++r) mx = fmaxf(mx, s[12][r]);
    mx = fmaxf(mx, __shfl_xor(mx, 16));
    mx = fmaxf(mx, __shfl_xor(mx, 32));
    float sum = 0.f;
#pragma unroll
    for (int nf = 0; nf < 12; ++nf)
#pragma unroll
      for (int r = 0; r < 4; ++r) {
        const float pv = __expf((s[nf][r] - mx) * SCALE_);
        s[nf][r] = pv; sum += pv;
      }
#pragma unroll
    for (int r = 0; r < 4; ++r) {
      const float pv = (hi == 0) ? __expf((s[12][r] - mx) * SCALE_) : 0.f;
      s[12][r] = pv; sum += pv;
    }
    sum += __shfl_xor(sum, 16);
    sum += __shfl_xor(sum, 32);
    const float inv = 1.f / sum;
#pragma unroll
    for (int nf = 0; nf < 13; ++nf)
#pragma unroll
      for (int r = 0; r < 4; ++r) s[nf][r] *= inv;

    f32x4 oa[7] = {};
    const int sLo = l15 + ((hi & 1) << 5);
    const int sHi = sLo + 16;
    const bool up = (hi >> 1) != 0;
#pragma unroll
    for (int kk = 0; kk < 7; ++kk) {
      const uint32_t a0 = cvt_pk_bf16(s[2 * kk][0], s[2 * kk][1]);
      const uint32_t a1 = cvt_pk_bf16(s[2 * kk][2], s[2 * kk][3]);
      const uint32_t w0a = (uint32_t)__shfl((int)a0, sLo, 64);
      const uint32_t w1a = (uint32_t)__shfl((int)a1, sLo, 64);
      const uint32_t w2a = (uint32_t)__shfl((int)a0, sHi, 64);
      const uint32_t w3a = (uint32_t)__shfl((int)a1, sHi, 64);
      uint32_t w0, w1, w2, w3;
      if (kk < 6) {
        const uint32_t b0 = cvt_pk_bf16(s[2 * kk + 1][0], s[2 * kk + 1][1]);
        const uint32_t b1 = cvt_pk_bf16(s[2 * kk + 1][2], s[2 * kk + 1][3]);
        const uint32_t w0b = (uint32_t)__shfl((int)b0, sLo, 64);
        const uint32_t w1b = (uint32_t)__shfl((int)b1, sLo, 64);
        const uint32_t w2b = (uint32_t)__shfl((int)b0, sHi, 64);
        const uint32_t w3b = (uint32_t)__shfl((int)b1, sHi, 64);
        w0 = up ? w0b : w0a; w1 = up ? w1b : w1a;
        w2 = up ? w2b : w2a; w3 = up ? w3b : w3a;
      } else {
        w0 = up ? 0u : w0a; w1 = up ? 0u : w1a;
        w2 = up ? 0u : w2a; w3 = up ? 0u : w3a;
      }
      union { uint32_t u[4]; bf16x8 v; } pa;
      pa.u[0] = w0; pa.u[1] = w1; pa.u[2] = w2; pa.u[3] = w3;
#pragma unroll
      for (int nf = 0; nf < 7; ++nf) {
        const int d = nf * 16 + l15;
        const bf16x8 vbf = *(const bf16x8*)(sV + d * 448 +
                              ((kk * 64 + hi * 16) ^ ((d & 3) << 4)));
        oa[nf] = __builtin_amdgcn_mfma_f32_16x16x32_bf16(pa.v, vbf, oa[nf], 0, 0, 0);
      }
    }
#pragma unroll
    for (int nf = 0; nf < 7; ++nf)
#pragma unroll
      for (int r = 0; r < 4; ++r) {
        const int q = q0 + hi * 4 + r;
        if (q < 196) obase[(size_t)q * 896 + nf * 16 + l15] = (__bf16)oa[nf][r];
      }
  }
}

// ------------------------------- launch ------------------------------------
extern "C" void kernel_launch(void* const* d_in, const int* in_sizes, int n_in,
                              void* d_out, int out_size, void* d_ws, size_t ws_size,
                              hipStream_t stream) {
  (void)in_sizes; (void)n_in; (void)out_size; (void)ws_size;
  const float* x_in  = (const float*)d_in[0];
  const float* bn1_g = (const float*)d_in[1];
  const float* bn1_b = (const float*)d_in[2];
  const float* Wqk   = (const float*)d_in[3];
  const float* bqk   = (const float*)d_in[4];
  const float* Wv    = (const float*)d_in[5];
  const float* bv    = (const float*)d_in[6];
  const float* Wo    = (const float*)d_in[7];
  const float* bo    = (const float*)d_in[8];
  const float* bn2_g = (const float*)d_in[9];
  const float* bn2_b = (const float*)d_in[10];
  const float* W1    = (const float*)d_in[11];
  const float* b1    = (const float*)d_in[12];
  const float* bn3_g = (const float*)d_in[13];
  const float* bn3_b = (const float*)d_in[14];
  const float* W2    = (const float*)d_in[15];
  const float* b2    = (const float*)d_in[16];

  char* ws = (char*)d_ws;
  __bf16* vTb  = (__bf16*)(ws + 0);           // 512x112x224 bf16 (blocked V^T)
  __bf16* wqkT = (__bf16*)(ws + 38535168);    // 6 x 1024 x 384
  __bf16* wvT  = (__bf16*)(ws + 43253760);    // 6 x 896 x 768
  __bf16* woT  = (__bf16*)(ws + 51511296);    // 6 x 768 x 896
  __bf16* w1T  = (__bf16*)(ws + 59768832);    // 6 x 768 x 768
  __bf16* w2T  = (__bf16*)(ws + 66846720);    // 6 x 768 x 768
  __bf16* xb16 = (__bf16*)(ws + 73924608);    // 12544x768 bf16 (THE residual)
  __bf16* qkb  = (__bf16*)(ws + 93192192);    // 12544x1024 bf16 (also f1 reuse)
  __bf16* obuf = (__bf16*)(ws + 141361152);   // 12544x896 bf16 (attn out; gelu out reuses)
  float*  part = (float*)(ws + 163840000);    // 196x768x2 f32
  float*  sc   = (float*)(ws + 165044224);    // 2x768 f32
  float*  sAcc = (float*)(ws + 165051392);    // 768x2 f32 stats accumulator
  __bf16* wqkT2= (__bf16*)(ws + 165057536);   // 1024x384 folded
  __bf16* wvT2 = (__bf16*)(ws + 165843968);   // 896x768 folded
  __bf16* w1T2 = (__bf16*)(ws + 167220224);   // 768x768 folded
  float*  bqk2 = (float*)(ws + 168399872);    // 1024
  float*  bv2  = (float*)(ws + 168403968);    // 896
  float*  b12  = (float*)(ws + 168407552);    // 768
  __bf16* f1b  = qkb;
  __bf16* gout = obuf;                        // GELU output reuses obuf region

  const dim3 tb(256);
  const dim3 tb512(512);

  transpose_cvt<<<dim3(32, 12, 6), dim3(32, 8), 0, stream>>>(Wqk, wqkT, 384, 1024);
  transpose_cvt<<<dim3(28, 24, 6), dim3(32, 8), 0, stream>>>(Wv,  wvT,  768, 896);
  transpose_cvt<<<dim3(24, 28, 6), dim3(32, 8), 0, stream>>>(Wo,  woT,  896, 768);
  transpose_cvt<<<dim3(24, 24, 6), dim3(32, 8), 0, stream>>>(W1,  w1T,  768, 768);
  transpose_cvt<<<dim3(24, 24, 6), dim3(32, 8), 0, stream>>>(W2,  w2T,  768, 768);
  cvt_bf16<<<9408, tb, 0, stream>>>(x_in, xb16);
  (void)hipMemsetAsync(sAcc, 0, 768 * 2 * sizeof(float), stream);
  (void)hipMemsetAsync(vTb, 0, (size_t)512 * 112 * 224 * 2, stream);  // zero pad

  // layer-0 bn1 stats (standalone, reads x_in fp32 exactly)
  bn_stats_part<<<dim3(3, 196), tb, 0, stream>>>(x_in, part);
  bn_stats_fin<<<3, tb, 0, stream>>>(part, bn1_g, bn1_b, sc);

  // XCD-grouped 1D grids: 8 * ceil(98/8)=13 * S
  const int gQK = 8 * 13 * 8;
  const int gV  = 8 * 13 * 7;
  const int gO  = 8 * 13 * 6;

  for (int i = 0; i < 6; ++i) {
    const __bf16* wqkT_i = wqkT + (size_t)i * 1024 * 384;
    const __bf16* wvT_i  = wvT  + (size_t)i * 896 * 768;
    const __bf16* woT_i  = woT  + (size_t)i * 768 * 896;
    const __bf16* w1T_i  = w1T  + (size_t)i * 768 * 768;
    const __bf16* w2T_i  = w2T  + (size_t)i * 768 * 768;

    // --- attention block ---  (sc holds bn1 scale/shift)
    fold_attn<<<1008, tb, 0, stream>>>(wqkT_i, wvT_i, bqk + i * 1024, bv + i * 896,
                                       sc, wqkT2, wvT2, bqk2, bv2);
    gemm128<0, 0, 1, 0><<<gQK, tb, 0, stream>>>(xb16 + 384, 768, wqkT2, 384,
                                                bqk2, qkb, nullptr, nullptr, 1024,
                                                nullptr, 98, 8);
    gemm128<2, 0, 0, 0><<<gV, tb, 0, stream>>>(wvT2, 768, xb16, 768,
                                               bv2, vTb, nullptr, nullptr, 12544,
                                               nullptr, 98, 7);
    attn_kernel<<<1024, tb512, 0, stream>>>(qkb, vTb, obuf);
    gemm128<1, 1, 1, 0><<<gO, tb, 0, stream>>>(obuf, 896, woT_i, 896,
                                               bo + i * 768, xb16, xb16, nullptr, 768,
                                               sAcc, 98, 6);

    // --- feedforward block ---
    bn_fin2<<<3, tb, 0, stream>>>(sAcc, bn2_g + i * 768, bn2_b + i * 768, sc);
    fold_ffn<<<480, tb, 0, stream>>>(w1T_i, b1 + i * 768, sc, w1T2, b12);
    gemm128<0, 1, 1, 0><<<gO, tb, 0, stream>>>(xb16, 768, w1T2, 768,
                                               b12, f1b, nullptr, nullptr, 768,
                                               sAcc, 98, 6);
    bn_fin2<<<3, tb, 0, stream>>>(sAcc, bn3_g + i * 768, bn3_b + i * 768, sc);
    bn_gelu_apply<<<9408, tb, 0, stream>>>(f1b, sc, gout);
    if (i < 5) {
      gemm128<1, 1, 1, 0><<<gO, tb, 0, stream>>>(gout, 768, w2T_i, 768,
                                                 b2 + i * 768, xb16, xb16, nullptr, 768,
                                                 sAcc, 98, 6);
      bn_fin2<<<3, tb, 0, stream>>>(sAcc, bn1_g + (i + 1) * 768, bn1_b + (i + 1) * 768, sc);
    } else {
      gemm128<1, 0, 1, 1><<<gO, tb, 0, stream>>>(gout, 768, w2T_i, 768,
                                                 b2 + i * 768, xb16, xb16,
                                                 (float*)d_out, 768,
                                                 nullptr, 98, 6);
    }
  }
}